// Round 7
// baseline (239.661 us; speedup 1.0000x reference)
//
#include <hip/hip_runtime.h>
#include <cstddef>

// Problem geometry (fixed by the reference)
constexpr int BB  = 16;                 // batch
constexpr int JJ  = 15;                 // joints
constexpr int MM  = 10;                 // bboxes
constexpr int CX  = 80, CY = 80, CZ = 20;
constexpr int NB  = CX * CY * CZ;       // 128000 voxels
constexpr int HMW = 240, HMH = 128;     // heatmap w,h
constexpr int TPB = 256;
constexpr int VEC = 4;                  // voxels per thread (contig in n)

typedef float f32x4 __attribute__((ext_vector_type(4)));  // clang vector: OK for nontemporal builtin

// n = ix*CY*CZ + iy*CZ + iz   (meshgrid 'ij', ravel)
// cube out: [B, J, NB] ; grids out: [B, NB, 3] appended after cubes.

__global__ __launch_bounds__(TPB) void project_kernel(
    const float* __restrict__ hm,      // [B,J,HMH,HMW]
    const float* __restrict__ gc,      // [B,3]
    const float* __restrict__ center,  // [B,2]
    const float* __restrict__ scale,   // [B]
    const float* __restrict__ Rm,      // [B,3,3]
    const float* __restrict__ Tm,      // [B,3,1]
    const float* __restrict__ fv,      // [B,2]
    const float* __restrict__ cv,      // [B,2]
    const float* __restrict__ kd,      // [B,3]
    const float* __restrict__ pd,      // [B,2]
    const float* __restrict__ bbox,    // [B,M,4]
    const float* __restrict__ dep,     // [B,M]
    const float* __restrict__ dnf,     // [B]
    float* __restrict__ out)           // cubes ++ grids
{
    const int blocksPerB = NB / (TPB * VEC);   // 125
    const int b  = blockIdx.x / blocksPerB;
    const int n0 = (blockIdx.x % blocksPerB) * (TPB * VEC) + threadIdx.x * VEC;

    // ---- block-uniform per-b parameters (scalarized by compiler) ----
    const float gcx = gc[b * 3 + 0], gcy = gc[b * 3 + 1], gcz = gc[b * 3 + 2];
    const float* R = Rm + b * 9;
    const float* T = Tm + b * 3;
    const float R0 = R[0], R1 = R[1], R2 = R[2];
    const float R3 = R[3], R4 = R[4], R5 = R[5];
    const float R6 = R[6], R7 = R[7], R8 = R[8];
    const float T0 = T[0], T1 = T[1], T2 = T[2];
    const float k0 = kd[b * 3 + 0], k1 = kd[b * 3 + 1], k2 = kd[b * 3 + 2];
    const float p0 = pd[b * 2 + 0], p1 = pd[b * 2 + 1];
    const float f0 = fv[b * 2 + 0], f1 = fv[b * 2 + 1];
    const float cc0 = cv[b * 2 + 0], cc1 = cv[b * 2 + 1];
    const float c0 = center[b * 2 + 0], c1 = center[b * 2 + 1];
    const float width = c0 * 2.0f, height = c1 * 2.0f;
    const float mxwh = fmaxf(width, height);
    const float h = 200.0f * scale[b];
    const float dn = dnf[b];

    // preload bboxes / depths (uniform, unrolled static indexing)
    float bx0[MM], bx1[MM], bx2[MM], bx3[MM], dv[MM];
#pragma unroll
    for (int m = 0; m < MM; ++m) {
        const float* bx = bbox + ((size_t)b * MM + m) * 4;
        bx0[m] = bx[0]; bx1[m] = bx[1]; bx2[m] = bx[2]; bx3[m] = bx[3];
        dv[m] = dep[b * MM + m];
    }

    float maxw[VEC];
    int   o00[VEC], o01[VEC], o10[VEC], o11[VEC];
    float w00[VEC], w01[VEC], w10[VEC], w11[VEC];
    float gxa[VEC], gya[VEC], gza[VEC];

#pragma unroll
    for (int v = 0; v < VEC; ++v) {
        const int n   = n0 + v;
        const int iz  = n % CZ;
        const int rem = n / CZ;
        const int iy  = rem % CY;
        const int ixg = rem / CY;

        // grid point (identical expression order to the validated kernel)
        const float gx = -4000.0f + (float)ixg * (8000.0f / 79.0f) + gcx;
        const float gy = -4000.0f + (float)iy  * (8000.0f / 79.0f) + gcy;
        const float gz = -1000.0f + (float)iz  * (2000.0f / 19.0f) + gcz;
        gxa[v] = gx; gya[v] = gy; gza[v] = gz;

        const float xc = R0 * gx + R1 * gy + R2 * gz - T0;
        const float yc = R3 * gx + R4 * gy + R5 * gz - T1;
        const float zc = R6 * gx + R7 * gy + R8 * gz - T2;

        const float invz = 1.0f / (zc + 1e-5f);
        const float ynx = xc * invz;
        const float yny = yc * invz;
        const float r2  = ynx * ynx + yny * yny;
        const float radial = 1.0f + k0 * r2 + k1 * r2 * r2 + k2 * r2 * r2 * r2;
        const float tn = p0 * yny + p1 * ynx;
        const float sm = radial + 2.0f * tn;
        const float ux = ynx * sm + p1 * r2;
        const float uy = yny * sm + p0 * r2;
        float xpix = f0 * ux + cc0;
        float ypix = f1 * uy + cc1;

        const bool bound = (xpix >= 0.0f) && (ypix >= 0.0f) &&
                           (xpix < width) && (ypix < height);
        xpix = fminf(fmaxf(xpix, -1.0f), mxwh);
        ypix = fminf(fmaxf(ypix, -1.0f), mxwh);

        const float ximg = (960.0f / h) * xpix + 960.0f * (-c0 / h + 0.5f);
        const float yimg = (512.0f / h) * ypix + 512.0f * (-c1 / h + 0.5f);
        const float xhm = ximg * (240.0f / 960.0f);
        const float yhm = yimg * (128.0f / 512.0f);

        const float sgx = fminf(fmaxf(xhm / 239.0f * 2.0f - 1.0f, -1.1f), 1.1f);
        const float sgy = fminf(fmaxf(yhm / 127.0f * 2.0f - 1.0f, -1.1f), 1.1f);
        const float fx = (sgx + 1.0f) * 0.5f * 239.0f;
        const float fy = (sgy + 1.0f) * 0.5f * 127.0f;
        const float fx0 = floorf(fx), fy0 = floorf(fy);
        const float wxf = fx - fx0, wyf = fy - fy0;

        const bool okx0 = (fx0 >= 0.0f) && (fx0 <= 239.0f);
        const bool okx1 = (fx0 + 1.0f >= 0.0f) && (fx0 + 1.0f <= 239.0f);
        const bool oky0 = (fy0 >= 0.0f) && (fy0 <= 127.0f);
        const bool oky1 = (fy0 + 1.0f >= 0.0f) && (fy0 + 1.0f <= 127.0f);
        const int x0 = min(max((int)fx0, 0), HMW - 1);
        const int x1 = min(max((int)fx0 + 1, 0), HMW - 1);
        const int y0 = min(max((int)fy0, 0), HMH - 1);
        const int y1 = min(max((int)fy0 + 1, 0), HMH - 1);
        w00[v] = (okx0 && oky0) ? (1.0f - wxf) * (1.0f - wyf) : 0.0f;
        w01[v] = (okx1 && oky0) ? wxf * (1.0f - wyf) : 0.0f;
        w10[v] = (okx0 && oky1) ? (1.0f - wxf) * wyf : 0.0f;
        w11[v] = (okx1 && oky1) ? wxf * wyf : 0.0f;
        o00[v] = y0 * HMW + x0;
        o01[v] = y0 * HMW + x1;
        o10[v] = y1 * HMW + x0;
        o11[v] = y1 * HMW + x1;

        float mw = 0.0f;
        if (bound) {
#pragma unroll
            for (int m = 0; m < MM; ++m) {
                const bool inb = (xhm >= bx0[m]) && (yhm >= bx1[m]) &&
                                 (xhm <= bx2[m]) && (yhm <= bx3[m]);
                const float dz = zc - dv[m] * dn;
                const float w = __expf(dz * dz * (-1.0f / (2.0f * 200.0f * 200.0f)));
                if (inb && dv[m] >= 0.0f) mw = fmaxf(mw, w);
            }
        }
        maxw[v] = mw;
    }

    // ---- grids output: 12 contiguous floats = 3x f32x4 (16B aligned) ----
    {
        float* gout = out + (size_t)BB * JJ * NB + ((size_t)b * NB + n0) * 3;
        f32x4 g0 = {gxa[0], gya[0], gza[0], gxa[1]};
        f32x4 g1 = {gya[1], gza[1], gxa[2], gya[2]};
        f32x4 g2 = {gza[2], gxa[3], gya[3], gza[3]};
        f32x4* gp = (f32x4*)gout;
        __builtin_nontemporal_store(g0, gp + 0);
        __builtin_nontemporal_store(g1, gp + 1);
        __builtin_nontemporal_store(g2, gp + 2);
    }

    // ---- per-joint bilinear sample & vector store ----
    const bool any = (maxw[0] > 0.0f) || (maxw[1] > 0.0f) ||
                     (maxw[2] > 0.0f) || (maxw[3] > 0.0f);
    const float* img = hm + (size_t)b * JJ * HMH * HMW;
    const size_t outbase = (size_t)b * JJ * NB + (size_t)n0;

    for (int j = 0; j < JJ; ++j) {
        f32x4 vv = {0.0f, 0.0f, 0.0f, 0.0f};
        if (any) {
            const float* p = img + (size_t)j * HMH * HMW;
#pragma unroll
            for (int v = 0; v < VEC; ++v) {
                float r = 0.0f;
                if (maxw[v] > 0.0f) {
                    const float s = p[o00[v]] * w00[v] + p[o01[v]] * w01[v] +
                                    p[o10[v]] * w10[v] + p[o11[v]] * w11[v];
                    r = fminf(fmaxf(s * maxw[v], 0.0f), 1.0f);
                }
                vv[v] = r;
            }
        }
        __builtin_nontemporal_store(vv, (f32x4*)(out + outbase + (size_t)j * NB));
    }
}

extern "C" void kernel_launch(void* const* d_in, const int* in_sizes, int n_in,
                              void* d_out, int out_size, void* d_ws, size_t ws_size,
                              hipStream_t stream) {
    const float* hm     = (const float*)d_in[0];
    const float* gc     = (const float*)d_in[1];
    const float* center = (const float*)d_in[2];
    const float* scale  = (const float*)d_in[3];
    const float* R      = (const float*)d_in[4];
    const float* T      = (const float*)d_in[5];
    const float* f      = (const float*)d_in[6];
    const float* c      = (const float*)d_in[7];
    const float* k      = (const float*)d_in[8];
    const float* p      = (const float*)d_in[9];
    const float* bbox   = (const float*)d_in[10];
    const float* dep    = (const float*)d_in[11];
    const float* dnf    = (const float*)d_in[12];
    float* out = (float*)d_out;

    const int blocksPerB = NB / (TPB * VEC);     // 125
    dim3 grid(BB * blocksPerB);                  // 2000 blocks
    dim3 block(TPB);
    project_kernel<<<grid, block, 0, stream>>>(hm, gc, center, scale, R, T, f, c,
                                               k, p, bbox, dep, dnf, out);
}

// Round 8
// 195.452 us; speedup vs baseline: 1.2262x; 1.2262x over previous
//
#include <hip/hip_runtime.h>
#include <cstddef>

// Problem geometry (fixed by the reference)
constexpr int BB  = 16;                 // batch
constexpr int JJ  = 15;                 // joints
constexpr int MM  = 10;                 // bboxes
constexpr int CX  = 80, CY = 80, CZ = 20;
constexpr int NB  = CX * CY * CZ;       // 128000 voxels
constexpr int HMW = 240, HMH = 128;     // heatmap w,h

// n = ix*CY*CZ + iy*CZ + iz   (meshgrid 'ij', ravel)
// cube out: [B, J, NB] ; grids out: [B, NB, 3] appended after cubes.
// NOTE (R7 post-mortem): VEC=4 + nontemporal stores regressed kernel ~20->~53us
// (VGPR/occupancy cliff + partial-line nt stores). Scalar 1-voxel/thread is at
// the ~23us HBM write floor; keep it.

__global__ __launch_bounds__(256) void project_kernel(
    const float* __restrict__ hm,      // [B,J,HMH,HMW]
    const float* __restrict__ gc,      // [B,3]
    const float* __restrict__ center,  // [B,2]
    const float* __restrict__ scale,   // [B]
    const float* __restrict__ Rm,      // [B,3,3]
    const float* __restrict__ Tm,      // [B,3,1]
    const float* __restrict__ fv,      // [B,2]
    const float* __restrict__ cv,      // [B,2]
    const float* __restrict__ kd,      // [B,3]
    const float* __restrict__ pd,      // [B,2]
    const float* __restrict__ bbox,    // [B,M,4]
    const float* __restrict__ dep,     // [B,M]
    const float* __restrict__ dnf,     // [B]
    float* __restrict__ out)           // cubes ++ grids
{
    const int blocksPerB = NB / 256;   // 500
    const int b = blockIdx.x / blocksPerB;
    const int n = (blockIdx.x % blocksPerB) * 256 + threadIdx.x;

    const int iz  = n % CZ;
    const int rem = n / CZ;
    const int iy  = rem % CY;
    const int ixg = rem / CY;

    // grid point (linspace endpoints inclusive)
    const float gx = -4000.0f + (float)ixg * (8000.0f / 79.0f) + gc[b * 3 + 0];
    const float gy = -4000.0f + (float)iy  * (8000.0f / 79.0f) + gc[b * 3 + 1];
    const float gz = -1000.0f + (float)iz  * (2000.0f / 19.0f) + gc[b * 3 + 2];

    // ---- projection: xcam = R p - T ----
    const float* R = Rm + b * 9;
    const float* T = Tm + b * 3;
    const float xc = R[0] * gx + R[1] * gy + R[2] * gz - T[0];
    const float yc = R[3] * gx + R[4] * gy + R[5] * gz - T[1];
    const float zc = R[6] * gx + R[7] * gy + R[8] * gz - T[2];

    const float invz = 1.0f / (zc + 1e-5f);
    const float ynx = xc * invz;
    const float yny = yc * invz;
    const float r2  = ynx * ynx + yny * yny;
    const float k0 = kd[b * 3 + 0], k1 = kd[b * 3 + 1], k2 = kd[b * 3 + 2];
    const float radial = 1.0f + k0 * r2 + k1 * r2 * r2 + k2 * r2 * r2 * r2;
    const float p0 = pd[b * 2 + 0], p1 = pd[b * 2 + 1];
    const float tn = p0 * yny + p1 * ynx;
    const float sm = radial + 2.0f * tn;
    const float ux = ynx * sm + p1 * r2;
    const float uy = yny * sm + p0 * r2;
    float xpix = fv[b * 2 + 0] * ux + cv[b * 2 + 0];
    float ypix = fv[b * 2 + 1] * uy + cv[b * 2 + 1];

    const float c0 = center[b * 2 + 0], c1 = center[b * 2 + 1];
    const float width = c0 * 2.0f, height = c1 * 2.0f;
    const bool bound = (xpix >= 0.0f) && (ypix >= 0.0f) &&
                       (xpix < width) && (ypix < height);
    const float mxwh = fmaxf(width, height);
    xpix = fminf(fmaxf(xpix, -1.0f), mxwh);
    ypix = fminf(fmaxf(ypix, -1.0f), mxwh);

    // ---- crop transform -> image coords -> heatmap coords ----
    const float h = 200.0f * scale[b];
    const float ximg = (960.0f / h) * xpix + 960.0f * (-c0 / h + 0.5f);
    const float yimg = (512.0f / h) * ypix + 512.0f * (-c1 / h + 0.5f);
    const float xhm = ximg * (240.0f / 960.0f);
    const float yhm = yimg * (128.0f / 512.0f);

    // ---- sample grid (normalized, clipped to [-1.1, 1.1]) ----
    const float sgx = fminf(fmaxf(xhm / 239.0f * 2.0f - 1.0f, -1.1f), 1.1f);
    const float sgy = fminf(fmaxf(yhm / 127.0f * 2.0f - 1.0f, -1.1f), 1.1f);
    const float fx = (sgx + 1.0f) * 0.5f * 239.0f;
    const float fy = (sgy + 1.0f) * 0.5f * 127.0f;
    const float fx0 = floorf(fx), fy0 = floorf(fy);
    const float wxf = fx - fx0, wyf = fy - fy0;

    const bool okx0 = (fx0 >= 0.0f) && (fx0 <= 239.0f);
    const bool okx1 = (fx0 + 1.0f >= 0.0f) && (fx0 + 1.0f <= 239.0f);
    const bool oky0 = (fy0 >= 0.0f) && (fy0 <= 127.0f);
    const bool oky1 = (fy0 + 1.0f >= 0.0f) && (fy0 + 1.0f <= 127.0f);
    const int x0 = min(max((int)fx0, 0), HMW - 1);
    const int x1 = min(max((int)fx0 + 1, 0), HMW - 1);
    const int y0 = min(max((int)fy0, 0), HMH - 1);
    const int y1 = min(max((int)fy0 + 1, 0), HMH - 1);
    const float w00 = (okx0 && oky0) ? (1.0f - wxf) * (1.0f - wyf) : 0.0f;
    const float w01 = (okx1 && oky0) ? wxf * (1.0f - wyf) : 0.0f;
    const float w10 = (okx0 && oky1) ? (1.0f - wxf) * wyf : 0.0f;
    const float w11 = (okx1 && oky1) ? wxf * wyf : 0.0f;

    // ---- max weight over bboxes (gaussian depth mask) ----
    float maxw = 0.0f;
    if (bound) {
        const float dn = dnf[b];
        for (int m = 0; m < MM; ++m) {
            const float d = dep[b * MM + m];
            const float* bx = bbox + ((size_t)b * MM + m) * 4;
            const bool inb = (xhm >= bx[0]) && (yhm >= bx[1]) &&
                             (xhm <= bx[2]) && (yhm <= bx[3]);
            const float dz = zc - d * dn;
            const float w = __expf(dz * dz * (-1.0f / (2.0f * 200.0f * 200.0f)));
            if (inb && d >= 0.0f) maxw = fmaxf(maxw, w);
        }
    }

    // ---- per-joint bilinear sample & write ----
    const size_t outbase = (size_t)b * JJ * NB + (size_t)n;
    if (maxw > 0.0f) {
        const float* img = hm + (size_t)b * JJ * HMH * HMW;
        const int o00 = y0 * HMW + x0;
        const int o01 = y0 * HMW + x1;
        const int o10 = y1 * HMW + x0;
        const int o11 = y1 * HMW + x1;
        for (int j = 0; j < JJ; ++j) {
            const float* p = img + (size_t)j * HMH * HMW;
            const float s = p[o00] * w00 + p[o01] * w01 +
                            p[o10] * w10 + p[o11] * w11;
            float v = s * maxw;
            v = fminf(fmaxf(v, 0.0f), 1.0f);
            out[outbase + (size_t)j * NB] = v;
        }
    } else {
        for (int j = 0; j < JJ; ++j)
            out[outbase + (size_t)j * NB] = 0.0f;
    }

    // ---- grids output ----
    float* gout = out + (size_t)BB * JJ * NB + ((size_t)b * NB + n) * 3;
    gout[0] = gx;
    gout[1] = gy;
    gout[2] = gz;
}

extern "C" void kernel_launch(void* const* d_in, const int* in_sizes, int n_in,
                              void* d_out, int out_size, void* d_ws, size_t ws_size,
                              hipStream_t stream) {
    const float* hm     = (const float*)d_in[0];
    const float* gc     = (const float*)d_in[1];
    const float* center = (const float*)d_in[2];
    const float* scale  = (const float*)d_in[3];
    const float* R      = (const float*)d_in[4];
    const float* T      = (const float*)d_in[5];
    const float* f      = (const float*)d_in[6];
    const float* c      = (const float*)d_in[7];
    const float* k      = (const float*)d_in[8];
    const float* p      = (const float*)d_in[9];
    const float* bbox   = (const float*)d_in[10];
    const float* dep    = (const float*)d_in[11];
    const float* dnf    = (const float*)d_in[12];
    float* out = (float*)d_out;

    const int blocksPerB = NB / 256;          // 500
    dim3 grid(BB * blocksPerB);               // 8000 blocks
    dim3 block(256);
    project_kernel<<<grid, block, 0, stream>>>(hm, gc, center, scale, R, T, f, c,
                                               k, p, bbox, dep, dnf, out);
}